// Round 14
// baseline (132.268 us; speedup 1.0000x reference)
//
#include <hip/hip_runtime.h>
#include <hip/hip_bf16.h>

#define B_DIM 8192
#define IN_DIM 2048
#define OUT_DIM 2048
#define NCH 128   // row-chunks for stats (64 rows each)

typedef __attribute__((ext_vector_type(4))) int i32x4;

// ---------------- Stage 1: per-column sum/sumsq/min/max (deterministic) --------
__global__ void k_stats(const float* __restrict__ x, float* __restrict__ psum,
                        float* __restrict__ psq, float* __restrict__ pmn,
                        float* __restrict__ pmx) {
    int col = blockIdx.x * 256 + threadIdx.x;
    int chunk = blockIdx.y;                       // 128 chunks x 64 rows
    const float* p = x + (size_t)chunk * 64 * IN_DIM + col;
    float s = 0.f, s2 = 0.f, mn = 3.0e38f, mx = -3.0e38f;
#pragma unroll 8
    for (int r = 0; r < 64; ++r) {
        float v = p[(size_t)r * IN_DIM];
        s += v;
        s2 = fmaf(v, v, s2);
        mn = fminf(mn, v);
        mx = fmaxf(mx, v);
    }
    psum[chunk * IN_DIM + col] = s;
    psq[chunk * IN_DIM + col] = s2;
    pmn[chunk * IN_DIM + col] = mn;
    pmx[chunk * IN_DIM + col] = mx;
}

// ---------------- Stage 2: finalize mean/var -> scale/shift + |xn| bound -------
__global__ void k_finalize(const float* __restrict__ psum, const float* __restrict__ psq,
                           const float* __restrict__ pmn, const float* __restrict__ pmx,
                           const float* __restrict__ gamma, const float* __restrict__ beta,
                           float* __restrict__ scale, float* __restrict__ shift,
                           float* __restrict__ bcol) {
    int c = blockIdx.x * 256 + threadIdx.x;
    float s = 0.f, s2 = 0.f, mn = 3.0e38f, mx = -3.0e38f;
#pragma unroll 8
    for (int ch = 0; ch < NCH; ++ch) {
        s += psum[ch * IN_DIM + c];
        s2 += psq[ch * IN_DIM + c];
        mn = fminf(mn, pmn[ch * IN_DIM + c]);
        mx = fmaxf(mx, pmx[ch * IN_DIM + c]);
    }
    float mean = s * (1.0f / B_DIM);
    float var = fmaf(-mean, mean, s2 * (1.0f / B_DIM));
    float sc = gamma[c] * rsqrtf(var + 1e-5f);
    float bt = fmaf(-mean, sc, beta[c]);
    scale[c] = sc;
    shift[c] = bt;
    bcol[c] = fmaxf(fabsf(fmaf(mn, sc, bt)), fabsf(fmaf(mx, sc, bt)));
}

// ---------------- Stage 2b: global max -> quant scales -------------------------
__global__ void k_scale(const float* __restrict__ bcol, float* __restrict__ sbuf) {
    __shared__ float red[4];
    int t = threadIdx.x;
    float m = 0.f;
#pragma unroll
    for (int i = 0; i < 8; ++i) m = fmaxf(m, bcol[t * 8 + i]);
#pragma unroll
    for (int off = 32; off; off >>= 1) m = fmaxf(m, __shfl_xor(m, off));
    if ((t & 63) == 0) red[t >> 6] = m;
    __syncthreads();
    if (t == 0) {
        float M = fmaxf(fmaxf(red[0], red[1]), fmaxf(red[2], red[3]));
        float s = M * (1.0f / 127.0f);
        sbuf[0] = s * (1.0f / 254.0f);  // s_lo: y = s_lo * (254*S_hi + S_lo)
        sbuf[1] = 127.0f / M;           // 1/s
    }
}

// ---------------- Stage 3: xn -> i8 dual-slice hi|lo [8192][4096] --------------
__global__ void k_prep_a(const float* __restrict__ x, const float* __restrict__ scale,
                         const float* __restrict__ shift, const float* __restrict__ sbuf,
                         unsigned char* __restrict__ Ai) {
    int row = blockIdx.x;
    int c0 = threadIdx.x * 8;
    float inv_s = sbuf[1];
    const float4* px = (const float4*)(x + (size_t)row * IN_DIM + c0);
    float4 v0 = px[0], v1 = px[1];
    const float4* ps = (const float4*)(scale + c0);
    float4 s0 = ps[0], s1 = ps[1];
    const float4* pb = (const float4*)(shift + c0);
    float4 b0 = pb[0], b1 = pb[1];
    float xs[8] = {v0.x, v0.y, v0.z, v0.w, v1.x, v1.y, v1.z, v1.w};
    float ss[8] = {s0.x, s0.y, s0.z, s0.w, s1.x, s1.y, s1.z, s1.w};
    float bb[8] = {b0.x, b0.y, b0.z, b0.w, b1.x, b1.y, b1.z, b1.w};
    union { unsigned char u[8]; uint2 v; } hb, lb;
#pragma unroll
    for (int j = 0; j < 8; ++j) {
        float xn = fmaf(xs[j], ss[j], bb[j]);
        float tq = xn * inv_s;              // |tq| <= 127 by construction
        float qh = rintf(tq);
        int ih = (int)qh;
        int il = (int)rintf((tq - qh) * 254.0f);  // |.| <= 127
        hb.u[j] = (unsigned char)ih;
        lb.u[j] = (unsigned char)il;
    }
    size_t base = (size_t)row * 4096 + c0;
    *(uint2*)(Ai + base) = hb.v;
    *(uint2*)(Ai + base + 2048) = lb.v;
}

// ---------------- Stage 4: weight sign -> i8 +-1 [2048][2048] ------------------
__global__ void k_prep_b(const float* __restrict__ w, unsigned char* __restrict__ Bi) {
    int row = blockIdx.x;
    int c0 = threadIdx.x * 8;
    const float4* pw = (const float4*)(w + (size_t)row * IN_DIM + c0);
    float4 v0 = pw[0], v1 = pw[1];
    float wv[8] = {v0.x, v0.y, v0.z, v0.w, v1.x, v1.y, v1.z, v1.w};
    union { unsigned char u[8]; uint2 v; } sb;
#pragma unroll
    for (int j = 0; j < 8; ++j) sb.u[j] = (wv[j] >= 0.0f) ? 0x01u : 0xFFu;
    *(uint2*)(Bi + (size_t)row * IN_DIM + c0) = sb.v;
}

// ---------------- Stage 5: 128x256 tile, 80KB LDS, 2 blocks/CU -----------------
// Mechanism change: inter-block overlap (m114). A single-buffered (16KB),
// B double-buffered (2x32KB) -> 80KB -> 2 blocks/CU; acc 64 VGPR; launch_bounds
// pins 128 VGPR so both blocks stay resident. Per tile: read all af + bp pair,
// MFMA n01, mid barrier (A overwrite-safe), stage A-next, MFMA n23, drain,
// barrier. Drains hidden by the co-resident block.
#define BM 128
#define BN 256
#define NWG ((B_DIM / BM) * (OUT_DIM / BN))  // 512
#define NKT 32
#define ATILE_B 16384                         // 128 rows x 128 B
#define BTILE_B 32768                         // 256 rows x 128 B

#define MEMF() asm volatile("" ::: "memory")
#define BARRIER() do { MEMF(); __builtin_amdgcn_s_barrier(); MEMF(); } while (0)
#define WAITVM(N) asm volatile("s_waitcnt vmcnt(" #N ")" ::: "memory")
#define WAITLGKM0() asm volatile("s_waitcnt lgkmcnt(0)" ::: "memory")

__device__ __forceinline__ void gload16(const void* g, void* l) {
    __builtin_amdgcn_global_load_lds(
        (const __attribute__((address_space(1))) void*)g,
        (__attribute__((address_space(3))) void*)l,
        16, 0, 0);
}

__global__ __launch_bounds__(512, 4) void k_gemm(const unsigned char* __restrict__ A,
                                                 const unsigned char* __restrict__ Bs,
                                                 const float* __restrict__ sbuf,
                                                 float* __restrict__ out) {
    __shared__ __align__(16) unsigned char sh[ATILE_B + 2 * BTILE_B];  // 80 KiB

    int bid = blockIdx.x;
    int swz = (bid & 7) * (NWG / 8) + (bid >> 3);
    int mt = swz >> 3, nt = swz & 7;             // 64 m-tiles x 8 n-tiles
    int m0 = mt * BM, n0 = nt * BN;

    int t = threadIdx.x;
    int lane = t & 63, w = t >> 6;
    int wm = w >> 2, wn = w & 3;                 // 2m x 4n waves; per-wave 64x64
    int lrow = lane & 15, lg = lane >> 4;

    int sl0 = (lg ^ (lane & 7)) << 4;            // ks=0 slot byte offset
    int sl1 = ((lg + 4) ^ (lane & 7)) << 4;      // ks=1

    int aRd = (wm * 64 + lrow) * 128;
    int bRd = (wn * 64 + lrow) * 128;

    // Block-wide staging: thread t -> row t>>3, slot (t&7), pre-swizzled source
    int trow = t >> 3;
    int tslot = (t & 7) ^ (trow & 7);

    unsigned char* Abuf = sh;                    // single-buffered A
    auto stageA = [&](int sub, int kt) {         // sub: 64-row chunk 0..1
        const unsigned char* src =
            A + (size_t)(m0 + sub * 64 + trow) * 4096 + kt * 128 + tslot * 16;
        gload16(src, Abuf + sub * 8192 + t * 16);
    };
    auto stageB = [&](unsigned char* bbuf, int sub, int kt) {  // sub 0..3
        const unsigned char* src =
            Bs + (size_t)(n0 + sub * 64 + trow) * 2048 + (kt & 15) * 128 + tslot * 16;
        gload16(src, bbuf + sub * 8192 + t * 16);
    };

    i32x4 acc[4][4] = {};

#define LDA(m, sl) (*(const i32x4*)&Abuf[aRd + (m) * 2048 + (sl)])
#define LDB(buf, n, sl) (*(const i32x4*)&(buf)[bRd + (n) * 2048 + (sl)])
// 16 MFMAs: n-pair {NP, NP+1} x 4m x 2ks
#define MFMA_NP(NP, BP)                                                            \
    do {                                                                           \
        __builtin_amdgcn_s_setprio(1);                                             \
        _Pragma("unroll") for (int ks = 0; ks < 2; ++ks)                           \
            _Pragma("unroll") for (int m = 0; m < 4; ++m)                          \
                _Pragma("unroll") for (int i = 0; i < 2; ++i)                      \
                    acc[m][(NP) + i] = __builtin_amdgcn_mfma_i32_16x16x64_i8(      \
                        af[m][ks], BP[i][ks], acc[m][(NP) + i], 0, 0, 0);          \
        __builtin_amdgcn_s_setprio(0);                                             \
    } while (0)

    // Prologue: stage A(0) + B(0) -> Bbuf0; drain; barrier.
    {
        unsigned char* B0 = sh + ATILE_B;
        stageA(0, 0); stageA(1, 0);
        stageB(B0, 0, 0); stageB(B0, 1, 0); stageB(B0, 2, 0); stageB(B0, 3, 0);
        WAITVM(0);
        BARRIER();
    }

#define TILE_BODY(T, PF)                                                               \
    do {                                                                               \
        unsigned char* Bc = sh + ATILE_B + ((T) & 1) * BTILE_B;                        \
        unsigned char* Bn = sh + ATILE_B + (((T) & 1) ^ 1) * BTILE_B;                  \
        bool pf = (PF);                                                                \
        int kn = (T) + 1;                                                              \
        i32x4 af[4][2];                                                                \
        _Pragma("unroll") for (int m = 0; m < 4; ++m) {                                \
            af[m][0] = LDA(m, sl0); af[m][1] = LDA(m, sl1); }                          \
        {                                                                              \
            i32x4 bp[2][2];                                                            \
            _Pragma("unroll") for (int i = 0; i < 2; ++i) {                            \
                bp[i][0] = LDB(Bc, i, sl0); bp[i][1] = LDB(Bc, i, sl1); }              \
            if (pf) { stageB(Bn, 0, kn); stageB(Bn, 1, kn);                            \
                      stageB(Bn, 2, kn); stageB(Bn, 3, kn); }                          \
            MFMA_NP(0, bp);                                                            \
        }                                                                              \
        WAITLGKM0();                                                                   \
        BARRIER();  /* all af reads done -> A overwrite safe */                        \
        if (pf) { stageA(0, kn); stageA(1, kn); }                                      \
        {                                                                              \
            i32x4 bp[2][2];                                                            \
            _Pragma("unroll") for (int i = 0; i < 2; ++i) {                            \
                bp[i][0] = LDB(Bc, 2 + i, sl0); bp[i][1] = LDB(Bc, 2 + i, sl1); }      \
            MFMA_NP(2, bp);                                                            \
        }                                                                              \
        if (pf) { WAITVM(0); }                                                         \
        WAITLGKM0();                                                                   \
        BARRIER();  /* publish A(T+1), B(T+1); Bc safe to overwrite next tile */       \
    } while (0)

    for (int T = 0; T < 16; ++T) TILE_BODY(T, true);

    // Exact fixup: S := 254*S_hi before accumulating the lo slice (fits i32).
#pragma unroll
    for (int m = 0; m < 4; ++m)
#pragma unroll
        for (int n = 0; n < 4; ++n) acc[m][n] = acc[m][n] * 254;

    for (int T = 16; T < NKT; ++T) TILE_BODY(T, T < NKT - 1);

    // Epilogue: y = s_lo * S, hardtanh; C/D map col=lane&15, row=(lane>>4)*4+reg
    float s_lo = sbuf[0];
#pragma unroll
    for (int m = 0; m < 4; ++m) {
#pragma unroll
        for (int n = 0; n < 4; ++n) {
#pragma unroll
            for (int r = 0; r < 4; ++r) {
                int row = m0 + wm * 64 + m * 16 + lg * 4 + r;
                int col = n0 + wn * 64 + n * 16 + lrow;
                float v = (float)acc[m][n][r] * s_lo;
                v = fminf(fmaxf(v, -1.0f), 1.0f);
                out[(size_t)row * OUT_DIM + col] = v;
            }
        }
    }
}

extern "C" void kernel_launch(void* const* d_in, const int* in_sizes, int n_in,
                              void* d_out, int out_size, void* d_ws, size_t ws_size,
                              hipStream_t stream) {
    const float* x = (const float*)d_in[0];
    const float* w = (const float*)d_in[1];
    const float* gamma = (const float*)d_in[2];
    const float* beta = (const float*)d_in[3];
    float* out = (float*)d_out;

    float* wsf = (float*)d_ws;
    float* psum = wsf;                                // NCH*2048 = 262144
    float* psq = wsf + 262144;
    float* pmn = wsf + 524288;
    float* pmx = wsf + 786432;
    float* scale = wsf + 1048576;                     // 2048
    float* shift = wsf + 1050624;                     // 2048
    float* bcol = wsf + 1052672;                      // 2048
    float* sbuf = wsf + 1054720;                      // 16
    unsigned char* Bi = (unsigned char*)(wsf + 1056768);       // 4 MB
    unsigned char* Ai = Bi + (size_t)OUT_DIM * IN_DIM;         // 32 MB

    k_stats<<<dim3(8, NCH), 256, 0, stream>>>(x, psum, psq, pmn, pmx);
    k_finalize<<<8, 256, 0, stream>>>(psum, psq, pmn, pmx, gamma, beta, scale, shift, bcol);
    k_scale<<<1, 256, 0, stream>>>(bcol, sbuf);
    k_prep_a<<<B_DIM, 256, 0, stream>>>(x, scale, shift, sbuf, Ai);
    k_prep_b<<<OUT_DIM, 256, 0, stream>>>(w, Bi);
    k_gemm<<<NWG, 512, 0, stream>>>(Ai, Bi, sbuf, out);
}

// Round 15
// 114.411 us; speedup vs baseline: 1.1561x; 1.1561x over previous
//
#include <hip/hip_runtime.h>
#include <hip/hip_bf16.h>

#define B_DIM 8192
#define IN_DIM 2048
#define OUT_DIM 2048
#define NCH 128   // row-chunks for stats (64 rows each)

typedef __attribute__((ext_vector_type(4))) int i32x4;

// ---------------- Stage 1: per-column sum/sumsq/min/max (deterministic) --------
__global__ void k_stats(const float* __restrict__ x, float* __restrict__ psum,
                        float* __restrict__ psq, float* __restrict__ pmn,
                        float* __restrict__ pmx) {
    int col = blockIdx.x * 256 + threadIdx.x;
    int chunk = blockIdx.y;                       // 128 chunks x 64 rows
    const float* p = x + (size_t)chunk * 64 * IN_DIM + col;
    float s = 0.f, s2 = 0.f, mn = 3.0e38f, mx = -3.0e38f;
#pragma unroll 8
    for (int r = 0; r < 64; ++r) {
        float v = p[(size_t)r * IN_DIM];
        s += v;
        s2 = fmaf(v, v, s2);
        mn = fminf(mn, v);
        mx = fmaxf(mx, v);
    }
    psum[chunk * IN_DIM + col] = s;
    psq[chunk * IN_DIM + col] = s2;
    pmn[chunk * IN_DIM + col] = mn;
    pmx[chunk * IN_DIM + col] = mx;
}

// ---------------- Stage 2: finalize mean/var -> scale/shift + |xn| bound -------
__global__ void k_finalize(const float* __restrict__ psum, const float* __restrict__ psq,
                           const float* __restrict__ pmn, const float* __restrict__ pmx,
                           const float* __restrict__ gamma, const float* __restrict__ beta,
                           float* __restrict__ scale, float* __restrict__ shift,
                           float* __restrict__ bcol) {
    int c = blockIdx.x * 256 + threadIdx.x;
    float s = 0.f, s2 = 0.f, mn = 3.0e38f, mx = -3.0e38f;
#pragma unroll 8
    for (int ch = 0; ch < NCH; ++ch) {
        s += psum[ch * IN_DIM + c];
        s2 += psq[ch * IN_DIM + c];
        mn = fminf(mn, pmn[ch * IN_DIM + c]);
        mx = fmaxf(mx, pmx[ch * IN_DIM + c]);
    }
    float mean = s * (1.0f / B_DIM);
    float var = fmaf(-mean, mean, s2 * (1.0f / B_DIM));
    float sc = gamma[c] * rsqrtf(var + 1e-5f);
    float bt = fmaf(-mean, sc, beta[c]);
    scale[c] = sc;
    shift[c] = bt;
    bcol[c] = fmaxf(fabsf(fmaf(mn, sc, bt)), fabsf(fmaf(mx, sc, bt)));
}

// ---------------- Stage 2b: global max -> quant scales -------------------------
__global__ void k_scale(const float* __restrict__ bcol, float* __restrict__ sbuf) {
    __shared__ float red[4];
    int t = threadIdx.x;
    float m = 0.f;
#pragma unroll
    for (int i = 0; i < 8; ++i) m = fmaxf(m, bcol[t * 8 + i]);
#pragma unroll
    for (int off = 32; off; off >>= 1) m = fmaxf(m, __shfl_xor(m, off));
    if ((t & 63) == 0) red[t >> 6] = m;
    __syncthreads();
    if (t == 0) {
        float M = fmaxf(fmaxf(red[0], red[1]), fmaxf(red[2], red[3]));
        float s = M * (1.0f / 127.0f);
        sbuf[0] = s * (1.0f / 254.0f);  // s_lo: y = s_lo * (254*S_hi + S_lo)
        sbuf[1] = 127.0f / M;           // 1/s
    }
}

// ---------------- Stage 3: xn -> i8 dual-slice hi|lo [8192][4096] --------------
__global__ void k_prep_a(const float* __restrict__ x, const float* __restrict__ scale,
                         const float* __restrict__ shift, const float* __restrict__ sbuf,
                         unsigned char* __restrict__ Ai) {
    int row = blockIdx.x;
    int c0 = threadIdx.x * 8;
    float inv_s = sbuf[1];
    const float4* px = (const float4*)(x + (size_t)row * IN_DIM + c0);
    float4 v0 = px[0], v1 = px[1];
    const float4* ps = (const float4*)(scale + c0);
    float4 s0 = ps[0], s1 = ps[1];
    const float4* pb = (const float4*)(shift + c0);
    float4 b0 = pb[0], b1 = pb[1];
    float xs[8] = {v0.x, v0.y, v0.z, v0.w, v1.x, v1.y, v1.z, v1.w};
    float ss[8] = {s0.x, s0.y, s0.z, s0.w, s1.x, s1.y, s1.z, s1.w};
    float bb[8] = {b0.x, b0.y, b0.z, b0.w, b1.x, b1.y, b1.z, b1.w};
    union { unsigned char u[8]; uint2 v; } hb, lb;
#pragma unroll
    for (int j = 0; j < 8; ++j) {
        float xn = fmaf(xs[j], ss[j], bb[j]);
        float tq = xn * inv_s;              // |tq| <= 127 by construction
        float qh = rintf(tq);
        int ih = (int)qh;
        int il = (int)rintf((tq - qh) * 254.0f);  // |.| <= 127
        hb.u[j] = (unsigned char)ih;
        lb.u[j] = (unsigned char)il;
    }
    size_t base = (size_t)row * 4096 + c0;
    *(uint2*)(Ai + base) = hb.v;
    *(uint2*)(Ai + base + 2048) = lb.v;
}

// ---------------- Stage 4: weight sign -> i8 +-1 [2048][2048] ------------------
__global__ void k_prep_b(const float* __restrict__ w, unsigned char* __restrict__ Bi) {
    int row = blockIdx.x;
    int c0 = threadIdx.x * 8;
    const float4* pw = (const float4*)(w + (size_t)row * IN_DIM + c0);
    float4 v0 = pw[0], v1 = pw[1];
    float wv[8] = {v0.x, v0.y, v0.z, v0.w, v1.x, v1.y, v1.z, v1.w};
    union { unsigned char u[8]; uint2 v; } sb;
#pragma unroll
    for (int j = 0; j < 8; ++j) sb.u[j] = (wv[j] >= 0.0f) ? 0x01u : 0xFFu;
    *(uint2*)(Bi + (size_t)row * IN_DIM + c0) = sb.v;
}

// ---------------- Stage 5: R13 skeleton, SINGLE barrier per tile ---------------
// A and B both double-buffered -> the only cross-wave hazards are "next tile
// staged" and "current-buffer reads done"; one tile-end {vmcnt(0), lgkmcnt(0),
// barrier} covers both IF all staging is issued early (B at ph0, A at ph1).
// Mid-tile wait+barrier deleted: current chunk1 (bpC/bpD) was staged >=2.5
// phases before the PREVIOUS tile-end barrier. Every load 2-3 phases old at
// its drain. i8 dual-slice hi|lo, exact fixup acc*=254, y = s_lo * S.
#define BM 256
#define BN 256
#define NWG ((B_DIM / BM) * (OUT_DIM / BN))  // 256
#define NKT 32
#define TILE_B 32768                          // 256 rows x 128 B

#define MEMF() asm volatile("" ::: "memory")
#define BARRIER() do { MEMF(); __builtin_amdgcn_s_barrier(); MEMF(); } while (0)
#define WAITVM(N) asm volatile("s_waitcnt vmcnt(" #N ")" ::: "memory")
#define WAITLGKM0() asm volatile("s_waitcnt lgkmcnt(0)" ::: "memory")

__device__ __forceinline__ void gload16(const void* g, void* l) {
    __builtin_amdgcn_global_load_lds(
        (const __attribute__((address_space(1))) void*)g,
        (__attribute__((address_space(3))) void*)l,
        16, 0, 0);
}

__global__ __launch_bounds__(512, 2) void k_gemm(const unsigned char* __restrict__ A,
                                                 const unsigned char* __restrict__ Bs,
                                                 const float* __restrict__ sbuf,
                                                 float* __restrict__ out) {
    __shared__ __align__(16) unsigned char sh[4 * TILE_B];  // [A0][B0][A1][B1]

    int bid = blockIdx.x;
    int swz = (bid & 7) * (NWG / 8) + (bid >> 3);
    int mt = swz >> 3, nt = swz & 7;
    int m0 = mt * BM, n0 = nt * BN;

    int t = threadIdx.x;
    int lane = t & 63, w = t >> 6;
    int wm = w >> 1, wn = w & 1;         // 4m x 2n waves; per-wave out 64 x 128
    int lrow = lane & 15, lg = lane >> 4;
    int lq = lane >> 3, lslot = lane & 7;
    int tsl = lslot ^ lq;

    int sl0 = (lg ^ (lane & 7)) << 4;          // ks=0 slot byte offset
    int sl1 = ((lg + 4) ^ (lane & 7)) << 4;    // ks=1

    int aRd = (wm * 64 + lrow) * 128;
    int bRd = (wn * 128 + lrow) * 128;

    auto stageA = [&](unsigned char* abuf, int j, int kt) {
        int q = wn * 4 + j;
        const unsigned char* src =
            A + (size_t)(m0 + wm * 64 + q * 8 + lq) * 4096 + kt * 128 + tsl * 16;
        gload16(src, abuf + wm * 8192 + q * 1024 + lane * 16);
    };
    auto stageB = [&](unsigned char* bbuf, int i, int j, int kt) {
        int cb = 2 * wn + i;
        int q = wm * 2 + j;
        const unsigned char* src =
            Bs + (size_t)(n0 + cb * 64 + q * 8 + lq) * 2048 + (kt & 15) * 128 + tsl * 16;
        gload16(src, bbuf + cb * 8192 + q * 1024 + lane * 16);
    };

    i32x4 acc[4][8] = {};

#define LDA(buf, m, sl) (*(const i32x4*)&(buf)[aRd + (m) * 2048 + (sl)])
#define LDB(buf, n, sl) (*(const i32x4*)&(buf)[bRd + (n) * 2048 + (sl)])
#define MFMA_PAIR(NP, BP)                                                          \
    do {                                                                           \
        __builtin_amdgcn_s_setprio(1);                                             \
        _Pragma("unroll") for (int ks = 0; ks < 2; ++ks)                           \
            _Pragma("unroll") for (int m = 0; m < 4; ++m)                          \
                _Pragma("unroll") for (int i = 0; i < 2; ++i)                      \
                    acc[m][(NP) + i] = __builtin_amdgcn_mfma_i32_16x16x64_i8(      \
                        af[m][ks], BP[i][ks], acc[m][(NP) + i], 0, 0, 0);          \
        __builtin_amdgcn_s_setprio(0);                                             \
    } while (0)

    i32x4 af[4][2];
    i32x4 bpA[2][2], bpB[2][2], bpC[2][2], bpD[2][2];

    // Prologue: stage tile0 fully; drain; read af + bpA.
    {
        unsigned char* A0b = sh;
        unsigned char* B0b = sh + TILE_B;
        stageA(A0b, 0, 0); stageA(A0b, 1, 0); stageA(A0b, 2, 0); stageA(A0b, 3, 0);
        stageB(B0b, 0, 0, 0); stageB(B0b, 0, 1, 0); stageB(B0b, 1, 0, 0); stageB(B0b, 1, 1, 0);
        WAITVM(0);
        BARRIER();
#pragma unroll
        for (int m = 0; m < 4; ++m) { af[m][0] = LDA(A0b, m, sl0); af[m][1] = LDA(A0b, m, sl1); }
#pragma unroll
        for (int i = 0; i < 2; ++i) { bpA[i][0] = LDB(B0b, i, sl0); bpA[i][1] = LDB(B0b, i, sl1); }
    }

#define TILE_BODY(T, PF)                                                               \
    do {                                                                               \
        const unsigned char* Ab = sh + ((T) & 1) * (2 * TILE_B);                       \
        const unsigned char* Bb = Ab + TILE_B;                                         \
        unsigned char* An = sh + (((T) & 1) ^ 1) * (2 * TILE_B);                       \
        unsigned char* Bn = An + TILE_B;                                               \
        bool pf = (PF);                                                                \
        int kn = (T) + 1;                                                              \
        /* ph0: issue all next-B; read bpB; MFMA n{0,1} */                             \
        if (pf) { stageB(Bn, 0, 0, kn); stageB(Bn, 0, 1, kn);                          \
                  stageB(Bn, 1, 0, kn); stageB(Bn, 1, 1, kn); }                        \
        _Pragma("unroll") for (int i = 0; i < 2; ++i) {                                \
            bpB[i][0] = LDB(Bb, 2 + i, sl0); bpB[i][1] = LDB(Bb, 2 + i, sl1); }        \
        MFMA_PAIR(0, bpA);                                                             \
        /* ph1: issue all next-A; read bpC; MFMA n{2,3} (no barrier) */                \
        if (pf) { stageA(An, 0, kn); stageA(An, 1, kn);                                \
                  stageA(An, 2, kn); stageA(An, 3, kn); }                              \
        _Pragma("unroll") for (int i = 0; i < 2; ++i) {                                \
            bpC[i][0] = LDB(Bb, 4 + i, sl0); bpC[i][1] = LDB(Bb, 4 + i, sl1); }        \
        MFMA_PAIR(2, bpB);                                                             \
        /* ph2: read bpD; MFMA n{4,5} */                                               \
        _Pragma("unroll") for (int i = 0; i < 2; ++i) {                                \
            bpD[i][0] = LDB(Bb, 6 + i, sl0); bpD[i][1] = LDB(Bb, 6 + i, sl1); }        \
        MFMA_PAIR(4, bpC);                                                             \
        /* ph3: MFMA n{6,7}; single tile-end drain + barrier; read next frags */       \
        MFMA_PAIR(6, bpD);                                                             \
        WAITVM(0);                                                                     \
        WAITLGKM0();                                                                   \
        BARRIER();                                                                     \
        if (pf) {                                                                      \
            _Pragma("unroll") for (int m = 0; m < 4; ++m) {                            \
                af[m][0] = LDA(An, m, sl0); af[m][1] = LDA(An, m, sl1); }              \
            _Pragma("unroll") for (int i = 0; i < 2; ++i) {                            \
                bpA[i][0] = LDB(Bn, i, sl0); bpA[i][1] = LDB(Bn, i, sl1); }            \
        }                                                                              \
    } while (0)

#pragma unroll 2
    for (int T = 0; T < 16; ++T) TILE_BODY(T, true);

    // Exact fixup: S := 254*S_hi before accumulating the lo slice (fits i32).
#pragma unroll
    for (int m = 0; m < 4; ++m)
#pragma unroll
        for (int n = 0; n < 8; ++n) acc[m][n] = acc[m][n] * 254;

#pragma unroll 2
    for (int T = 16; T < NKT; ++T) TILE_BODY(T, T < NKT - 1);

    // Epilogue: y = s_lo * S, hardtanh; C/D map col=lane&15, row=(lane>>4)*4+reg
    float s_lo = sbuf[0];
#pragma unroll
    for (int m = 0; m < 4; ++m) {
#pragma unroll
        for (int n = 0; n < 8; ++n) {
#pragma unroll
            for (int r = 0; r < 4; ++r) {
                int row = m0 + wm * 64 + m * 16 + lg * 4 + r;
                int col = n0 + wn * 128 + n * 16 + lrow;
                float v = (float)acc[m][n][r] * s_lo;
                v = fminf(fmaxf(v, -1.0f), 1.0f);
                out[(size_t)row * OUT_DIM + col] = v;
            }
        }
    }
}

extern "C" void kernel_launch(void* const* d_in, const int* in_sizes, int n_in,
                              void* d_out, int out_size, void* d_ws, size_t ws_size,
                              hipStream_t stream) {
    const float* x = (const float*)d_in[0];
    const float* w = (const float*)d_in[1];
    const float* gamma = (const float*)d_in[2];
    const float* beta = (const float*)d_in[3];
    float* out = (float*)d_out;

    float* wsf = (float*)d_ws;
    float* psum = wsf;                                // NCH*2048 = 262144
    float* psq = wsf + 262144;
    float* pmn = wsf + 524288;
    float* pmx = wsf + 786432;
    float* scale = wsf + 1048576;                     // 2048
    float* shift = wsf + 1050624;                     // 2048
    float* bcol = wsf + 1052672;                      // 2048
    float* sbuf = wsf + 1054720;                      // 16
    unsigned char* Bi = (unsigned char*)(wsf + 1056768);       // 4 MB
    unsigned char* Ai = Bi + (size_t)OUT_DIM * IN_DIM;         // 32 MB

    k_stats<<<dim3(8, NCH), 256, 0, stream>>>(x, psum, psq, pmn, pmx);
    k_finalize<<<8, 256, 0, stream>>>(psum, psq, pmn, pmx, gamma, beta, scale, shift, bcol);
    k_scale<<<1, 256, 0, stream>>>(bcol, sbuf);
    k_prep_a<<<B_DIM, 256, 0, stream>>>(x, scale, shift, sbuf, Ai);
    k_prep_b<<<OUT_DIM, 256, 0, stream>>>(w, Bi);
    k_gemm<<<NWG, 512, 0, stream>>>(Ai, Bi, sbuf, out);
}

// Round 16
// 113.035 us; speedup vs baseline: 1.1702x; 1.0122x over previous
//
#include <hip/hip_runtime.h>
#include <hip/hip_bf16.h>

#define B_DIM 8192
#define IN_DIM 2048
#define OUT_DIM 2048
#define NCH 128   // row-chunks for stats (64 rows each)

typedef __attribute__((ext_vector_type(4))) int i32x4;

// ---------------- Stage 1: per-column sum/sumsq/min/max (deterministic) --------
// Also deterministically zeroes the atomicMax slot (graph replays re-zero it).
__global__ void k_stats(const float* __restrict__ x, float* __restrict__ psum,
                        float* __restrict__ psq, float* __restrict__ pmn,
                        float* __restrict__ pmx, int* __restrict__ Mslot) {
    if (blockIdx.x == 0 && blockIdx.y == 0 && threadIdx.x == 0) Mslot[0] = 0;
    int col = blockIdx.x * 256 + threadIdx.x;
    int chunk = blockIdx.y;                       // 128 chunks x 64 rows
    const float* p = x + (size_t)chunk * 64 * IN_DIM + col;
    float s = 0.f, s2 = 0.f, mn = 3.0e38f, mx = -3.0e38f;
#pragma unroll 8
    for (int r = 0; r < 64; ++r) {
        float v = p[(size_t)r * IN_DIM];
        s += v;
        s2 = fmaf(v, v, s2);
        mn = fminf(mn, v);
        mx = fmaxf(mx, v);
    }
    psum[chunk * IN_DIM + col] = s;
    psq[chunk * IN_DIM + col] = s2;
    pmn[chunk * IN_DIM + col] = mn;
    pmx[chunk * IN_DIM + col] = mx;
}

// ---------------- Stage 2: finalize -> scale/shift + fused global-max ----------
__global__ void k_finalize(const float* __restrict__ psum, const float* __restrict__ psq,
                           const float* __restrict__ pmn, const float* __restrict__ pmx,
                           const float* __restrict__ gamma, const float* __restrict__ beta,
                           float* __restrict__ scale, float* __restrict__ shift,
                           int* __restrict__ Mslot) {
    __shared__ float red[4];
    int t = threadIdx.x;
    int c = blockIdx.x * 256 + t;
    float s = 0.f, s2 = 0.f, mn = 3.0e38f, mx = -3.0e38f;
#pragma unroll 8
    for (int ch = 0; ch < NCH; ++ch) {
        s += psum[ch * IN_DIM + c];
        s2 += psq[ch * IN_DIM + c];
        mn = fminf(mn, pmn[ch * IN_DIM + c]);
        mx = fmaxf(mx, pmx[ch * IN_DIM + c]);
    }
    float mean = s * (1.0f / B_DIM);
    float var = fmaf(-mean, mean, s2 * (1.0f / B_DIM));
    float sc = gamma[c] * rsqrtf(var + 1e-5f);
    float bt = fmaf(-mean, sc, beta[c]);
    scale[c] = sc;
    shift[c] = bt;
    float bc = fmaxf(fabsf(fmaf(mn, sc, bt)), fabsf(fmaf(mx, sc, bt)));
    // block max -> one atomicMax (positive float bits compare as ints)
#pragma unroll
    for (int off = 32; off; off >>= 1) bc = fmaxf(bc, __shfl_xor(bc, off));
    if ((t & 63) == 0) red[t >> 6] = bc;
    __syncthreads();
    if (t == 0) {
        float m = fmaxf(fmaxf(red[0], red[1]), fmaxf(red[2], red[3]));
        atomicMax(Mslot, __float_as_int(m));
    }
}

// ---------------- Stage 3: xn -> i8 dual-slice hi|lo [8192][4096] --------------
__global__ void k_prep_a(const float* __restrict__ x, const float* __restrict__ scale,
                         const float* __restrict__ shift, const int* __restrict__ Mslot,
                         unsigned char* __restrict__ Ai) {
    int row = blockIdx.x;
    int c0 = threadIdx.x * 8;
    float M = __int_as_float(Mslot[0]);
    float inv_s = 127.0f / M;
    const float4* px = (const float4*)(x + (size_t)row * IN_DIM + c0);
    float4 v0 = px[0], v1 = px[1];
    const float4* ps = (const float4*)(scale + c0);
    float4 s0 = ps[0], s1 = ps[1];
    const float4* pb = (const float4*)(shift + c0);
    float4 b0 = pb[0], b1 = pb[1];
    float xs[8] = {v0.x, v0.y, v0.z, v0.w, v1.x, v1.y, v1.z, v1.w};
    float ss[8] = {s0.x, s0.y, s0.z, s0.w, s1.x, s1.y, s1.z, s1.w};
    float bb[8] = {b0.x, b0.y, b0.z, b0.w, b1.x, b1.y, b1.z, b1.w};
    union { unsigned char u[8]; uint2 v; } hb, lb;
#pragma unroll
    for (int j = 0; j < 8; ++j) {
        float xn = fmaf(xs[j], ss[j], bb[j]);
        float tq = xn * inv_s;              // |tq| <= 127 by construction
        float qh = rintf(tq);
        int ih = (int)qh;
        int il = (int)rintf((tq - qh) * 254.0f);  // |.| <= 127
        hb.u[j] = (unsigned char)ih;
        lb.u[j] = (unsigned char)il;
    }
    size_t base = (size_t)row * 4096 + c0;
    *(uint2*)(Ai + base) = hb.v;
    *(uint2*)(Ai + base + 2048) = lb.v;
}

// ---------------- Stage 4: weight sign -> i8 +-1 [2048][2048] ------------------
__global__ void k_prep_b(const float* __restrict__ w, unsigned char* __restrict__ Bi) {
    int row = blockIdx.x;
    int c0 = threadIdx.x * 8;
    const float4* pw = (const float4*)(w + (size_t)row * IN_DIM + c0);
    float4 v0 = pw[0], v1 = pw[1];
    float wv[8] = {v0.x, v0.y, v0.z, v0.w, v1.x, v1.y, v1.z, v1.w};
    union { unsigned char u[8]; uint2 v; } sb;
#pragma unroll
    for (int j = 0; j < 8; ++j) sb.u[j] = (wv[j] >= 0.0f) ? 0x01u : 0xFFu;
    *(uint2*)(Bi + (size_t)row * IN_DIM + c0) = sb.v;
}

// ---------------- Stage 5: R13-exact GEMM (proven 87.4us config) ---------------
// i8 dual-slice hi|lo on the R5 skeleton: reg-prefetched fragments, two
// barriers/tile (mid WAITVM(3) + tile-end WAITVM(0)), exact fixup acc*=254,
// y = s_lo * S with s_lo = M/(127*254). B k-index repeats per slice.
#define BM 256
#define BN 256
#define NWG ((B_DIM / BM) * (OUT_DIM / BN))  // 256
#define NKT 32
#define TILE_B 32768                          // 256 rows x 128 B

#define MEMF() asm volatile("" ::: "memory")
#define BARRIER() do { MEMF(); __builtin_amdgcn_s_barrier(); MEMF(); } while (0)
#define WAITVM(N) asm volatile("s_waitcnt vmcnt(" #N ")" ::: "memory")
#define WAITLGKM0() asm volatile("s_waitcnt lgkmcnt(0)" ::: "memory")

__device__ __forceinline__ void gload16(const void* g, void* l) {
    __builtin_amdgcn_global_load_lds(
        (const __attribute__((address_space(1))) void*)g,
        (__attribute__((address_space(3))) void*)l,
        16, 0, 0);
}

__global__ __launch_bounds__(512, 2) void k_gemm(const unsigned char* __restrict__ A,
                                                 const unsigned char* __restrict__ Bs,
                                                 const int* __restrict__ Mslot,
                                                 float* __restrict__ out) {
    __shared__ __align__(16) unsigned char sh[4 * TILE_B];  // 128 KiB

    int bid = blockIdx.x;
    int swz = (bid & 7) * (NWG / 8) + (bid >> 3);
    int mt = swz >> 3, nt = swz & 7;
    int m0 = mt * BM, n0 = nt * BN;

    int t = threadIdx.x;
    int lane = t & 63, w = t >> 6;
    int wm = w >> 1, wn = w & 1;         // 4m x 2n waves; per-wave out 64 x 128
    int lrow = lane & 15, lg = lane >> 4;
    int lq = lane >> 3, lslot = lane & 7;
    int tsl = lslot ^ lq;

    int sl0 = (lg ^ (lane & 7)) << 4;          // ks=0 slot byte offset
    int sl1 = ((lg + 4) ^ (lane & 7)) << 4;    // ks=1

    int aRd = (wm * 64 + lrow) * 128;
    int bRd = (wn * 128 + lrow) * 128;

    auto stageA = [&](unsigned char* abuf, int j, int kt) {
        int q = wn * 4 + j;
        const unsigned char* src =
            A + (size_t)(m0 + wm * 64 + q * 8 + lq) * 4096 + kt * 128 + tsl * 16;
        gload16(src, abuf + wm * 8192 + q * 1024 + lane * 16);
    };
    auto stageB = [&](unsigned char* bbuf, int i, int j, int kt) {
        int cb = 2 * wn + i;
        int q = wm * 2 + j;
        const unsigned char* src =
            Bs + (size_t)(n0 + cb * 64 + q * 8 + lq) * 2048 + (kt & 15) * 128 + tsl * 16;
        gload16(src, bbuf + cb * 8192 + q * 1024 + lane * 16);
    };

    i32x4 acc[4][8] = {};

#define LDA(buf, m, sl) (*(const i32x4*)&(buf)[aRd + (m) * 2048 + (sl)])
#define LDB(buf, n, sl) (*(const i32x4*)&(buf)[bRd + (n) * 2048 + (sl)])
#define MFMA_PAIR(NP, BP)                                                          \
    do {                                                                           \
        __builtin_amdgcn_s_setprio(1);                                             \
        _Pragma("unroll") for (int ks = 0; ks < 2; ++ks)                           \
            _Pragma("unroll") for (int m = 0; m < 4; ++m)                          \
                _Pragma("unroll") for (int i = 0; i < 2; ++i)                      \
                    acc[m][(NP) + i] = __builtin_amdgcn_mfma_i32_16x16x64_i8(      \
                        af[m][ks], BP[i][ks], acc[m][(NP) + i], 0, 0, 0);          \
        __builtin_amdgcn_s_setprio(0);                                             \
    } while (0)

    i32x4 af[4][2];
    i32x4 bpA[2][2], bpB[2][2], bpC[2][2], bpD[2][2];

    // Prologue: stage tile0 A + B chunk0; drain; issue B chunk1; read frags.
    {
        unsigned char* A0b = sh;
        unsigned char* B0b = sh + TILE_B;
        stageA(A0b, 0, 0); stageA(A0b, 1, 0); stageB(B0b, 0, 0, 0);
        stageB(B0b, 0, 1, 0); stageA(A0b, 2, 0); stageA(A0b, 3, 0);
        WAITVM(0);
        BARRIER();
        stageB(B0b, 1, 0, 0); stageB(B0b, 1, 1, 0);
#pragma unroll
        for (int m = 0; m < 4; ++m) { af[m][0] = LDA(A0b, m, sl0); af[m][1] = LDA(A0b, m, sl1); }
#pragma unroll
        for (int i = 0; i < 2; ++i) { bpA[i][0] = LDB(B0b, i, sl0); bpA[i][1] = LDB(B0b, i, sl1); }
    }

#define TILE_BODY(T, PF)                                                               \
    do {                                                                               \
        const unsigned char* Ab = sh + ((T) & 1) * (2 * TILE_B);                       \
        const unsigned char* Bb = Ab + TILE_B;                                         \
        unsigned char* An = sh + (((T) & 1) ^ 1) * (2 * TILE_B);                       \
        unsigned char* Bn = An + TILE_B;                                               \
        bool pf = (PF);                                                                \
        int kn = (T) + 1;                                                              \
        if (pf) { stageA(An, 0, kn); stageA(An, 1, kn); stageB(Bn, 0, 0, kn); }        \
        _Pragma("unroll") for (int i = 0; i < 2; ++i) {                                \
            bpB[i][0] = LDB(Bb, 2 + i, sl0); bpB[i][1] = LDB(Bb, 2 + i, sl1); }        \
        MFMA_PAIR(0, bpA);                                                             \
        if (pf) { WAITVM(3); } else { WAITVM(0); }                                     \
        WAITLGKM0();                                                                   \
        BARRIER();                                                                     \
        if (pf) { stageB(Bn, 0, 1, kn); stageA(An, 2, kn); stageA(An, 3, kn); }        \
        _Pragma("unroll") for (int i = 0; i < 2; ++i) {                                \
            bpC[i][0] = LDB(Bb, 4 + i, sl0); bpC[i][1] = LDB(Bb, 4 + i, sl1); }        \
        MFMA_PAIR(2, bpB);                                                             \
        _Pragma("unroll") for (int i = 0; i < 2; ++i) {                                \
            bpD[i][0] = LDB(Bb, 6 + i, sl0); bpD[i][1] = LDB(Bb, 6 + i, sl1); }        \
        MFMA_PAIR(4, bpC);                                                             \
        WAITVM(0);                                                                     \
        WAITLGKM0();                                                                   \
        BARRIER();                                                                     \
        if (pf) { stageB(Bn, 1, 0, kn); stageB(Bn, 1, 1, kn); }                        \
        MFMA_PAIR(6, bpD);                                                             \
        if (pf) {                                                                      \
            _Pragma("unroll") for (int m = 0; m < 4; ++m) {                            \
                af[m][0] = LDA(An, m, sl0); af[m][1] = LDA(An, m, sl1); }              \
            _Pragma("unroll") for (int i = 0; i < 2; ++i) {                            \
                bpA[i][0] = LDB(Bn, i, sl0); bpA[i][1] = LDB(Bn, i, sl1); }            \
        }                                                                              \
    } while (0)

#pragma unroll 2
    for (int T = 0; T < 16; ++T) TILE_BODY(T, true);

    // Exact fixup: S := 254*S_hi before accumulating the lo slice (fits i32).
#pragma unroll
    for (int m = 0; m < 4; ++m)
#pragma unroll
        for (int n = 0; n < 8; ++n) acc[m][n] = acc[m][n] * 254;

#pragma unroll 2
    for (int T = 16; T < NKT; ++T) TILE_BODY(T, T < NKT - 1);

    // Epilogue: y = s_lo * S, hardtanh; C/D map col=lane&15, row=(lane>>4)*4+reg
    float s_lo = __int_as_float(Mslot[0]) * (1.0f / (127.0f * 254.0f));
#pragma unroll
    for (int m = 0; m < 4; ++m) {
#pragma unroll
        for (int n = 0; n < 8; ++n) {
#pragma unroll
            for (int r = 0; r < 4; ++r) {
                int row = m0 + wm * 64 + m * 16 + lg * 4 + r;
                int col = n0 + wn * 128 + n * 16 + lrow;
                float v = (float)acc[m][n][r] * s_lo;
                v = fminf(fmaxf(v, -1.0f), 1.0f);
                out[(size_t)row * OUT_DIM + col] = v;
            }
        }
    }
}

extern "C" void kernel_launch(void* const* d_in, const int* in_sizes, int n_in,
                              void* d_out, int out_size, void* d_ws, size_t ws_size,
                              hipStream_t stream) {
    const float* x = (const float*)d_in[0];
    const float* w = (const float*)d_in[1];
    const float* gamma = (const float*)d_in[2];
    const float* beta = (const float*)d_in[3];
    float* out = (float*)d_out;

    float* wsf = (float*)d_ws;
    float* psum = wsf;                                // NCH*2048 = 262144
    float* psq = wsf + 262144;
    float* pmn = wsf + 524288;
    float* pmx = wsf + 786432;
    float* scale = wsf + 1048576;                     // 2048
    float* shift = wsf + 1050624;                     // 2048
    int* Mslot = (int*)(wsf + 1052672);               // fused atomicMax slot
    unsigned char* Bi = (unsigned char*)(wsf + 1054720);       // 4 MB
    unsigned char* Ai = Bi + (size_t)OUT_DIM * IN_DIM;         // 32 MB

    k_stats<<<dim3(8, NCH), 256, 0, stream>>>(x, psum, psq, pmn, pmx, Mslot);
    k_finalize<<<8, 256, 0, stream>>>(psum, psq, pmn, pmx, gamma, beta, scale, shift, Mslot);
    k_prep_a<<<B_DIM, 256, 0, stream>>>(x, scale, shift, Mslot, Ai);
    k_prep_b<<<OUT_DIM, 256, 0, stream>>>(w, Bi);
    k_gemm<<<NWG, 512, 0, stream>>>(Ai, Bi, Mslot, out);
}